// Round 3
// baseline (501.930 us; speedup 1.0000x reference)
//
#include <hip/hip_runtime.h>
#include <cstdint>

// Fused decoder layer, bf16 MFMA pipeline.
// B=4 S=1024 D=1024 H=16 HD=64, rows R=4096.

typedef __bf16 bf16_t;
typedef __bf16 bf16x8 __attribute__((ext_vector_type(8)));
typedef __bf16 bf16x4 __attribute__((ext_vector_type(4)));
typedef float  f32x4  __attribute__((ext_vector_type(4)));

static __device__ __forceinline__ void g2l16(const void* g, void* l) {
  // global -> LDS direct copy, 16B per lane; dst is wave-uniform base, HW adds lane*16.
  __builtin_amdgcn_global_load_lds(
      (__attribute__((address_space(1))) void*)(uintptr_t)g,
      (__attribute__((address_space(3))) void*)l, 16, 0, 0);
}

// ---------------- conversion & packing ----------------
__global__ __launch_bounds__(256) void cvt_f32_bf16(const float* __restrict__ in,
                                                    bf16_t* __restrict__ out, int n) {
  int i = (blockIdx.x * 256 + threadIdx.x) * 4;
  if (i >= n) return;
  float4 v = *(const float4*)(in + i);
  bf16x4 o = { (bf16_t)v.x, (bf16_t)v.y, (bf16_t)v.z, (bf16_t)v.w };
  *(bf16x4*)(out + i) = o;
}

__global__ __launch_bounds__(256) void pack_bias3(const float* __restrict__ a,
                                                  const float* __restrict__ b,
                                                  const float* __restrict__ c,
                                                  float* __restrict__ o) {
  int i = blockIdx.x * 256 + threadIdx.x;  // 0..3071
  o[i] = (i < 1024) ? a[i] : (i < 2048 ? b[i - 1024] : c[i - 2048]);
}

// ---------------- GEMM: C[M,N] = A[M,K] @ Bt[N,K]^T (+epilogue) ----------------
// 128x128 tile, BK=32, 4 waves (2x2), each wave 64x64 = 4x4 MFMA 16x16x32 frags.
// EPI: 0=QKV scatter (bf16, V transposed per head), 1=Wo(+resid fp32 out),
//      2=up(GELU, bf16 out), 3=down(+resid fp32 out)
template<int EPI>
__global__ __launch_bounds__(256) void gemm_bt(
    const bf16_t* __restrict__ A, const bf16_t* __restrict__ Bt,
    const float* __restrict__ bias, const float* __restrict__ resid,
    float* __restrict__ outf, bf16_t* __restrict__ outb,
    bf16_t* __restrict__ outb2, bf16_t* __restrict__ outb3,
    int M, int N, int K)
{
  __shared__ __align__(16) bf16_t As[128 * 32];
  __shared__ __align__(16) bf16_t Bs[128 * 32];
  const int nbm = M >> 7;
  const int bm = blockIdx.x % nbm;       // consecutive blocks share the B (weight) panel
  const int bn = blockIdx.x / nbm;
  const int lane = threadIdx.x & 63, wid = threadIdx.x >> 6;
  const int wm = wid >> 1, wn = wid & 1;
  const int lr = lane & 15, lk = lane >> 4;   // frag row / k-group
  const int rowA0 = bm * 128, rowB0 = bn * 128;

  f32x4 acc[4][4] = {};

  // staging geometry: tile = 128 rows x 64B; wave stages 2x1024B segments of each tile
  const int seg0 = (wid * 2) * 1024;
  const int boff0 = seg0 + lane * 16;          // byte offset in tile, lane's first 16B
  const int r0 = boff0 >> 6, cb0 = (boff0 & 63) >> 1;   // row, col(elem) in tile
  const int boff1 = boff0 + 1024;
  const int r1 = boff1 >> 6, cb1 = (boff1 & 63) >> 1;

  for (int k0 = 0; k0 < K; k0 += 32) {
    g2l16(A  + (size_t)(rowA0 + r0) * K + k0 + cb0, (char*)As + seg0);
    g2l16(A  + (size_t)(rowA0 + r1) * K + k0 + cb1, (char*)As + seg0 + 1024);
    g2l16(Bt + (size_t)(rowB0 + r0) * K + k0 + cb0, (char*)Bs + seg0);
    g2l16(Bt + (size_t)(rowB0 + r1) * K + k0 + cb1, (char*)Bs + seg0 + 1024);
    __syncthreads();
    bf16x8 af[4], bb[4];
#pragma unroll
    for (int i = 0; i < 4; ++i)
      af[i] = *(const bf16x8*)(As + (wm * 64 + i * 16 + lr) * 32 + lk * 8);
#pragma unroll
    for (int j = 0; j < 4; ++j)
      bb[j] = *(const bf16x8*)(Bs + (wn * 64 + j * 16 + lr) * 32 + lk * 8);
#pragma unroll
    for (int i = 0; i < 4; ++i)
#pragma unroll
      for (int j = 0; j < 4; ++j)
        acc[i][j] = __builtin_amdgcn_mfma_f32_16x16x32_bf16(af[i], bb[j], acc[i][j], 0, 0, 0);
    __syncthreads();
  }

  // epilogue: C frag mapping col=lane&15, row=(lane>>4)*4+t  [m89-verified]
#pragma unroll
  for (int i = 0; i < 4; ++i) {
    const int grb = bm * 128 + wm * 64 + i * 16 + lk * 4;
#pragma unroll
    for (int j = 0; j < 4; ++j) {
      const int gc = bn * 128 + wn * 64 + j * 16 + lr;
#pragma unroll
      for (int t = 0; t < 4; ++t) {
        const int gr = grb + t;
        float v = acc[i][j][t];
        if (EPI == 0) {
          v += bias[gc];
          const int which = gc >> 10, w2 = gc & 1023, h = w2 >> 6, hd = w2 & 63;
          const int b = gr >> 10, s = gr & 1023;
          const bf16_t bv = (bf16_t)v;
          if (which == 0)      outb [(((size_t)b * 16 + h) * 1024 + s) * 64 + hd] = bv;
          else if (which == 1) outb2[(((size_t)b * 16 + h) * 1024 + s) * 64 + hd] = bv;
          else                 outb3[(((size_t)b * 16 + h) * 64 + hd) * 1024 + s] = bv; // V^T
        } else if (EPI == 1 || EPI == 3) {
          v += bias[gc] + resid[(size_t)gr * N + gc];
          outf[(size_t)gr * N + gc] = v;
        } else {  // EPI == 2: exact GELU
          v += bias[gc];
          const float gelu = 0.5f * v * (1.0f + erff(v * 0.70710678118654752440f));
          outb[(size_t)gr * N + gc] = (bf16_t)gelu;
        }
      }
    }
  }
}

// ---------------- flash attention (causal) ----------------
// grid (S/64, B*H), 256 thr = 4 independent waves; wave owns 16 q rows.
// Q,K: [bh][s][64] bf16; V: [bh][64][s] bf16 (transposed); ctx out: [b*s][h*64+hd] bf16.
__global__ __launch_bounds__(256) void attn_fwd(
    const bf16_t* __restrict__ Q, const bf16_t* __restrict__ Kv,
    const bf16_t* __restrict__ VT, bf16_t* __restrict__ ctx)
{
  const int qb = blockIdx.x, bh = blockIdx.y;
  const int lane = threadIdx.x & 63, wid = threadIdx.x >> 6;
  const int lr = lane & 15, lkg = lane >> 4;
  const int q0 = qb * 64 + wid * 16;
  const bf16_t* Qp = Q  + (size_t)bh * 1024 * 64;
  const bf16_t* Kp = Kv + (size_t)bh * 1024 * 64;
  const bf16_t* Vp = VT + (size_t)bh * 64 * 1024;

  bf16x8 qf[2];
#pragma unroll
  for (int kk = 0; kk < 2; ++kk)
    qf[kk] = *(const bf16x8*)(Qp + (size_t)(q0 + lr) * 64 + kk * 32 + lkg * 8);

  f32x4 cacc[4] = {};
  float m_i[4], l_i[4];
#pragma unroll
  for (int r = 0; r < 4; ++r) { m_i[r] = -1e30f; l_i[r] = 0.f; }

  __shared__ __align__(16) bf16_t Pl[4][16][72];  // per-wave P tile, padded (bank spread)

  const int ntiles = (q0 + 16 + 63) >> 6;  // kv0 of last tile <= q0 (alignment argument)
  for (int kt = 0; kt < ntiles; ++kt) {
    const int kv0 = kt << 6;
    f32x4 sacc[4] = {};
#pragma unroll
    for (int nb = 0; nb < 4; ++nb)
#pragma unroll
      for (int kk = 0; kk < 2; ++kk) {
        bf16x8 kf = *(const bf16x8*)(Kp + (size_t)(kv0 + nb * 16 + lr) * 64 + kk * 32 + lkg * 8);
        sacc[nb] = __builtin_amdgcn_mfma_f32_16x16x32_bf16(qf[kk], kf, sacc[nb], 0, 0, 0);
      }
    float sv[4][4];
    const bool domask = (kv0 + 63) > q0;
#pragma unroll
    for (int nb = 0; nb < 4; ++nb)
#pragma unroll
      for (int r = 0; r < 4; ++r) {
        float s = sacc[nb][r] * 0.125f;           // 1/sqrt(64)
        if (domask) {
          const int kv = kv0 + nb * 16 + lr;
          const int qq = q0 + lkg * 4 + r;
          if (kv > qq) s = -1e30f;
        }
        sv[nb][r] = s;
      }
    // online softmax: row = q, reduce over 16 lanes of the 16-group (cols)
    float scl[4], lt[4];
#pragma unroll
    for (int r = 0; r < 4; ++r) {
      float m = fmaxf(fmaxf(sv[0][r], sv[1][r]), fmaxf(sv[2][r], sv[3][r]));
      m = fmaxf(m, __shfl_xor(m, 1));
      m = fmaxf(m, __shfl_xor(m, 2));
      m = fmaxf(m, __shfl_xor(m, 4));
      m = fmaxf(m, __shfl_xor(m, 8));
      const float mnew = fmaxf(m_i[r], m);
      scl[r] = __expf(m_i[r] - mnew);
      m_i[r] = mnew;
      lt[r] = 0.f;
    }
#pragma unroll
    for (int nb = 0; nb < 4; ++nb)
#pragma unroll
      for (int r = 0; r < 4; ++r) {
        const float p = __expf(sv[nb][r] - m_i[r]);
        lt[r] += p;
        Pl[wid][lkg * 4 + r][nb * 16 + lr] = (bf16_t)p;
      }
#pragma unroll
    for (int r = 0; r < 4; ++r) {
      float l = lt[r];
      l += __shfl_xor(l, 1);
      l += __shfl_xor(l, 2);
      l += __shfl_xor(l, 4);
      l += __shfl_xor(l, 8);
      l_i[r] = l_i[r] * scl[r] + l;
    }
#pragma unroll
    for (int db = 0; db < 4; ++db)
#pragma unroll
      for (int r = 0; r < 4; ++r)
        cacc[db][r] *= scl[r];
    // PV: A = P (LDS re-layout), B = V^T rows (contiguous)
#pragma unroll
    for (int kk = 0; kk < 2; ++kk) {
      bf16x8 pf = *(const bf16x8*)(&Pl[wid][lr][kk * 32 + lkg * 8]);
#pragma unroll
      for (int db = 0; db < 4; ++db) {
        bf16x8 vf = *(const bf16x8*)(Vp + (size_t)(db * 16 + lr) * 1024 + kv0 + kk * 32 + lkg * 8);
        cacc[db] = __builtin_amdgcn_mfma_f32_16x16x32_bf16(pf, vf, cacc[db], 0, 0, 0);
      }
    }
  }
  const int b = bh >> 4, h = bh & 15;
#pragma unroll
  for (int db = 0; db < 4; ++db)
#pragma unroll
    for (int r = 0; r < 4; ++r) {
      const int q = q0 + lkg * 4 + r;
      const float o = cacc[db][r] / l_i[r];
      ctx[((size_t)(b * 1024 + q)) * 1024 + h * 64 + db * 16 + lr] = (bf16_t)o;
    }
}

// ---------------- row LayerNorm (D=1024), fp32 in, fp32 + optional bf16 out ----------------
__global__ __launch_bounds__(256) void ln_fwd(const float* __restrict__ in,
                                              const float* __restrict__ gw,
                                              const float* __restrict__ bw,
                                              float* __restrict__ outf,
                                              bf16_t* __restrict__ outb)
{
  const int row = blockIdx.x;
  const float4 v = ((const float4*)(in + (size_t)row * 1024))[threadIdx.x];
  float s  = v.x + v.y + v.z + v.w;
  float ss = v.x * v.x + v.y * v.y + v.z * v.z + v.w * v.w;
#pragma unroll
  for (int o = 32; o > 0; o >>= 1) {
    s  += __shfl_down(s, o);
    ss += __shfl_down(ss, o);
  }
  __shared__ float rs[4], rss[4];
  const int wid = threadIdx.x >> 6, lane = threadIdx.x & 63;
  if (lane == 0) { rs[wid] = s; rss[wid] = ss; }
  __syncthreads();
  const float S  = rs[0] + rs[1] + rs[2] + rs[3];
  const float SS = rss[0] + rss[1] + rss[2] + rss[3];
  const float mu = S * (1.f / 1024.f);
  const float var = SS * (1.f / 1024.f) - mu * mu;
  const float rstd = rsqrtf(var + 1e-7f);
  const float4 g4 = ((const float4*)gw)[threadIdx.x];
  const float4 b4 = ((const float4*)bw)[threadIdx.x];
  float4 o;
  o.x = (v.x - mu) * rstd * g4.x + b4.x;
  o.y = (v.y - mu) * rstd * g4.y + b4.y;
  o.z = (v.z - mu) * rstd * g4.z + b4.z;
  o.w = (v.w - mu) * rstd * g4.w + b4.w;
  if (outf) ((float4*)(outf + (size_t)row * 1024))[threadIdx.x] = o;
  if (outb) {
    bf16x4 ob = { (bf16_t)o.x, (bf16_t)o.y, (bf16_t)o.z, (bf16_t)o.w };
    *(bf16x4*)(outb + (size_t)row * 1024 + threadIdx.x * 4) = ob;
  }
}

// ---------------- launch ----------------
extern "C" void kernel_launch(void* const* d_in, const int* in_sizes, int n_in,
                              void* d_out, int out_size, void* d_ws, size_t ws_size,
                              hipStream_t stream) {
  (void)in_sizes; (void)n_in; (void)out_size; (void)ws_size;
  const float* X   = (const float*)d_in[0];
  const float* Wq  = (const float*)d_in[1];
  const float* bq  = (const float*)d_in[2];
  const float* Wk  = (const float*)d_in[3];
  const float* bk  = (const float*)d_in[4];
  const float* Wv  = (const float*)d_in[5];
  const float* bv  = (const float*)d_in[6];
  const float* Wo  = (const float*)d_in[7];
  const float* bo  = (const float*)d_in[8];
  const float* g1  = (const float*)d_in[9];
  const float* b1  = (const float*)d_in[10];
  const float* Wup = (const float*)d_in[11];
  const float* bup = (const float*)d_in[12];
  const float* Wdn = (const float*)d_in[13];
  const float* bdn = (const float*)d_in[14];
  const float* g2  = (const float*)d_in[15];
  const float* b2  = (const float*)d_in[16];
  float* out = (float*)d_out;

  char* w = (char*)d_ws;
  auto carve = [&](size_t bytes) { char* p = w; w += (bytes + 255) & ~255ull; return p; };
  bf16_t* Xb    = (bf16_t*)carve(4096ull * 1024 * 2);
  bf16_t* Wqkvb = (bf16_t*)carve(3072ull * 1024 * 2);
  bf16_t* Wob   = (bf16_t*)carve(1024ull * 1024 * 2);
  bf16_t* Wupb  = (bf16_t*)carve(4096ull * 1024 * 2);
  bf16_t* Wdnb  = (bf16_t*)carve(1024ull * 4096 * 2);
  bf16_t* Qb    = (bf16_t*)carve(64ull * 1024 * 64 * 2);
  bf16_t* Kb    = (bf16_t*)carve(64ull * 1024 * 64 * 2);
  bf16_t* VTb   = (bf16_t*)carve(64ull * 64 * 1024 * 2);
  bf16_t* CTXb  = (bf16_t*)carve(4096ull * 1024 * 2);
  bf16_t* X1b   = (bf16_t*)carve(4096ull * 1024 * 2);
  bf16_t* UPb   = (bf16_t*)carve(4096ull * 4096 * 2);
  float*  bias3 = (float*) carve(3072ull * 4);
  float*  res1  = (float*) carve(4096ull * 1024 * 4);   // reused for res2
  float*  X1f   = (float*) carve(4096ull * 1024 * 4);

  cvt_f32_bf16<<<4096, 256, 0, stream>>>(X,   Xb, 4096 * 1024);
  cvt_f32_bf16<<<1024, 256, 0, stream>>>(Wq,  Wqkvb,               1024 * 1024);
  cvt_f32_bf16<<<1024, 256, 0, stream>>>(Wk,  Wqkvb + 1024 * 1024, 1024 * 1024);
  cvt_f32_bf16<<<1024, 256, 0, stream>>>(Wv,  Wqkvb + 2048 * 1024, 1024 * 1024);
  cvt_f32_bf16<<<1024, 256, 0, stream>>>(Wo,  Wob,  1024 * 1024);
  cvt_f32_bf16<<<4096, 256, 0, stream>>>(Wup, Wupb, 4096 * 1024);
  cvt_f32_bf16<<<4096, 256, 0, stream>>>(Wdn, Wdnb, 1024 * 4096);
  pack_bias3<<<12, 256, 0, stream>>>(bq, bk, bv, bias3);

  // QKV projection + scatter (V transposed per head)
  gemm_bt<0><<<32 * 24, 256, 0, stream>>>(Xb, Wqkvb, bias3, nullptr,
                                          nullptr, Qb, Kb, VTb, 4096, 3072, 1024);
  // causal flash attention
  attn_fwd<<<dim3(16, 64), 256, 0, stream>>>(Qb, Kb, VTb, CTXb);
  // O projection + residual (X) -> res1 (fp32)
  gemm_bt<1><<<32 * 8, 256, 0, stream>>>(CTXb, Wob, bo, X,
                                         res1, nullptr, nullptr, nullptr, 4096, 1024, 1024);
  // LN1 -> X1 fp32 + bf16
  ln_fwd<<<4096, 256, 0, stream>>>(res1, g1, b1, X1f, X1b);
  // FFN up + exact GELU -> bf16
  gemm_bt<2><<<32 * 32, 256, 0, stream>>>(X1b, Wupb, bup, nullptr,
                                          nullptr, UPb, nullptr, nullptr, 4096, 4096, 1024);
  // FFN down + residual (X1) -> res1 (fp32, reuse)
  gemm_bt<3><<<32 * 8, 256, 0, stream>>>(UPb, Wdnb, bdn, X1f,
                                         res1, nullptr, nullptr, nullptr, 4096, 1024, 4096);
  // LN2 -> output fp32
  ln_fwd<<<4096, 256, 0, stream>>>(res1, g2, b2, out, nullptr);
}

// Round 5
// 435.491 us; speedup vs baseline: 1.1526x; 1.1526x over previous
//
#include <hip/hip_runtime.h>
#include <cstdint>

// Fused decoder layer, bf16 MFMA pipeline.
// B=4 S=1024 D=1024 H=16 HD=64, rows R=4096.

typedef __bf16 bf16_t;
typedef __bf16 bf16x8 __attribute__((ext_vector_type(8)));
typedef __bf16 bf16x4 __attribute__((ext_vector_type(4)));
typedef float  f32x4  __attribute__((ext_vector_type(4)));
typedef float  f32x16 __attribute__((ext_vector_type(16)));
typedef uint32_t u32x4 __attribute__((ext_vector_type(4)));

static __device__ __forceinline__ void g2l16(const void* g, void* l) {
  // global -> LDS direct copy, 16B per lane; dst is wave-uniform base, HW adds lane*16.
  __builtin_amdgcn_global_load_lds(
      (__attribute__((address_space(1))) void*)(uintptr_t)g,
      (__attribute__((address_space(3))) void*)l, 16, 0, 0);
}

// ---------------- conversion & packing ----------------
__global__ __launch_bounds__(256) void cvt_f32_bf16(const float* __restrict__ in,
                                                    bf16_t* __restrict__ out, int n) {
  int i = (blockIdx.x * 256 + threadIdx.x) * 4;
  if (i >= n) return;
  float4 v = *(const float4*)(in + i);
  bf16x4 o = { (bf16_t)v.x, (bf16_t)v.y, (bf16_t)v.z, (bf16_t)v.w };
  *(bf16x4*)(out + i) = o;
}

__global__ __launch_bounds__(256) void pack_bias3(const float* __restrict__ a,
                                                  const float* __restrict__ b,
                                                  const float* __restrict__ c,
                                                  float* __restrict__ o) {
  int i = blockIdx.x * 256 + threadIdx.x;  // 0..3071
  o[i] = (i < 1024) ? a[i] : (i < 2048 ? b[i - 1024] : c[i - 2048]);
}

// ---------------- GEMM: C[M,N] = A[M,K] @ Bt[N,K]^T (+epilogue) ----------------
// 128x128 tile, BK=32, 4 waves (2x2), each wave 64x64 = 4x4 MFMA 16x16x32 frags.
// EPI: 0=QKV scatter (bf16, V transposed per head), 1=Wo(+resid fp32 out),
//      2=up(GELU, bf16 out), 3=down(+resid fp32 out)
template<int EPI>
__global__ __launch_bounds__(256) void gemm_bt(
    const bf16_t* __restrict__ A, const bf16_t* __restrict__ Bt,
    const float* __restrict__ bias, const float* __restrict__ resid,
    float* __restrict__ outf, bf16_t* __restrict__ outb,
    bf16_t* __restrict__ outb2, bf16_t* __restrict__ outb3,
    int M, int N, int K)
{
  __shared__ __align__(16) bf16_t As[128 * 32];
  __shared__ __align__(16) bf16_t Bs[128 * 32];
  const int nbm = M >> 7;
  const int bm = blockIdx.x % nbm;       // consecutive blocks share the B (weight) panel
  const int bn = blockIdx.x / nbm;
  const int lane = threadIdx.x & 63, wid = threadIdx.x >> 6;
  const int wm = wid >> 1, wn = wid & 1;
  const int lr = lane & 15, lk = lane >> 4;   // frag row / k-group
  const int rowA0 = bm * 128, rowB0 = bn * 128;

  f32x4 acc[4][4] = {};

  // staging geometry: tile = 128 rows x 64B; wave stages 2x1024B segments of each tile
  const int seg0 = (wid * 2) * 1024;
  const int boff0 = seg0 + lane * 16;          // byte offset in tile, lane's first 16B
  const int r0 = boff0 >> 6, cb0 = (boff0 & 63) >> 1;   // row, col(elem) in tile
  const int boff1 = boff0 + 1024;
  const int r1 = boff1 >> 6, cb1 = (boff1 & 63) >> 1;

  for (int k0 = 0; k0 < K; k0 += 32) {
    g2l16(A  + (size_t)(rowA0 + r0) * K + k0 + cb0, (char*)As + seg0);
    g2l16(A  + (size_t)(rowA0 + r1) * K + k0 + cb1, (char*)As + seg0 + 1024);
    g2l16(Bt + (size_t)(rowB0 + r0) * K + k0 + cb0, (char*)Bs + seg0);
    g2l16(Bt + (size_t)(rowB0 + r1) * K + k0 + cb1, (char*)Bs + seg0 + 1024);
    __syncthreads();
    bf16x8 af[4], bb[4];
#pragma unroll
    for (int i = 0; i < 4; ++i)
      af[i] = *(const bf16x8*)(As + (wm * 64 + i * 16 + lr) * 32 + lk * 8);
#pragma unroll
    for (int j = 0; j < 4; ++j)
      bb[j] = *(const bf16x8*)(Bs + (wn * 64 + j * 16 + lr) * 32 + lk * 8);
#pragma unroll
    for (int i = 0; i < 4; ++i)
#pragma unroll
      for (int j = 0; j < 4; ++j)
        acc[i][j] = __builtin_amdgcn_mfma_f32_16x16x32_bf16(af[i], bb[j], acc[i][j], 0, 0, 0);
    __syncthreads();
  }

  // epilogue: C frag mapping col=lane&15, row=(lane>>4)*4+t  [m89-verified]
#pragma unroll
  for (int i = 0; i < 4; ++i) {
    const int grb = bm * 128 + wm * 64 + i * 16 + lk * 4;
#pragma unroll
    for (int j = 0; j < 4; ++j) {
      const int gc = bn * 128 + wn * 64 + j * 16 + lr;
#pragma unroll
      for (int t = 0; t < 4; ++t) {
        const int gr = grb + t;
        float v = acc[i][j][t];
        if (EPI == 0) {
          v += bias[gc];
          const int which = gc >> 10, w2 = gc & 1023, h = w2 >> 6, hd = w2 & 63;
          const int b = gr >> 10, s = gr & 1023;
          const bf16_t bv = (bf16_t)v;
          if (which == 0)      outb [(((size_t)b * 16 + h) * 1024 + s) * 64 + hd] = bv;
          else if (which == 1) outb2[(((size_t)b * 16 + h) * 1024 + s) * 64 + hd] = bv;
          else                 outb3[(((size_t)b * 16 + h) * 64 + hd) * 1024 + s] = bv; // V^T
        } else if (EPI == 1 || EPI == 3) {
          v += bias[gc] + resid[(size_t)gr * N + gc];
          outf[(size_t)gr * N + gc] = v;
        } else {  // EPI == 2: exact GELU
          v += bias[gc];
          const float gelu = 0.5f * v * (1.0f + erff(v * 0.70710678118654752440f));
          outb[(size_t)gr * N + gc] = (bf16_t)gelu;
        }
      }
    }
  }
}

// ---------------- flash attention (causal), swapped-operand 32x32 ----------------
// grid (8, B*H), 256 thr = 4 independent waves; wave owns one 32-row q-tile.
// Block bx owns q-tiles {2bx, 2bx+1, 30-2bx, 31-2bx} -> exactly 66 tile-iters/block.
// Q,K: [bh][s][64] bf16; V: [bh][64][s] bf16 (d-major); ctx out: [b*s][h*64+hd] bf16.
// S^T = mfma(A=K, B=Q): lane q=lane&31, kv=(r&3)+8*(r>>2)+4*hi (m74/m101 layout).
// O^T = mfma(A=V^T, B=P^T): lane q=lane&31 again -> softmax state stays lane-local.
__global__ __launch_bounds__(256) void attn_fwd2(
    const bf16_t* __restrict__ Q, const bf16_t* __restrict__ Kv,
    const bf16_t* __restrict__ VT, bf16_t* __restrict__ ctx)
{
  const int bx = blockIdx.x, bh = blockIdx.y;
  const int lane = threadIdx.x & 63, wid = threadIdx.x >> 6;
  const int lq = lane & 31, hi = lane >> 5;
  const int qt = (wid < 2) ? (2 * bx + wid) : (28 - 2 * bx + wid); // wid2->30-2bx, wid3->31-2bx
  const int q0 = qt * 32;
  const bf16_t* Qp = Q  + (size_t)bh * 1024 * 64;
  const bf16_t* Kp = Kv + (size_t)bh * 1024 * 64;
  const bf16_t* Vp = VT + (size_t)bh * 64 * 1024;

  // Q B-frags (col=q=lane&31, k=d=(db*16 + hi*8 + t)), resident all kernel
  bf16x8 qf[4];
#pragma unroll
  for (int db = 0; db < 4; ++db)
    qf[db] = *(const bf16x8*)(Qp + (size_t)(q0 + lq) * 64 + db * 16 + hi * 8);

  f32x16 oacc[2] = {};          // O^T tiles dt=0,1: row d=dt*32+crow(r,hi), col q=lq
  float m_i = -1e30f, l_i = 0.f;

  const int ntiles = qt + 1;
  for (int kt = 0; kt < ntiles; ++kt) {
    const int kv0 = kt << 5;
    // ---- QK^T (S^T[kv][q]) ----
    f32x16 s = {};
#pragma unroll
    for (int db = 0; db < 4; ++db) {
      bf16x8 kf = *(const bf16x8*)(Kp + (size_t)(kv0 + lq) * 64 + db * 16 + hi * 8);
      s = __builtin_amdgcn_mfma_f32_32x32x16_bf16(kf, qf[db], s, 0, 0, 0);
    }
    // ---- scale + causal mask (only diagonal tile needs masking) ----
    float p[16];
    const bool diag = (kv0 == q0);
#pragma unroll
    for (int r = 0; r < 16; ++r) {
      float v = s[r] * 0.125f;                       // 1/sqrt(64)
      if (diag) {
        const int kvr = (r & 3) + 8 * (r >> 2) + 4 * hi;
        if (kvr > lq) v = -1e30f;
      }
      p[r] = v;
    }
    // ---- online softmax, q = lane&31 (one shfl to merge hi-halves) ----
    float mt = p[0];
#pragma unroll
    for (int r = 1; r < 16; ++r) mt = fmaxf(mt, p[r]);
    mt = fmaxf(mt, __shfl_xor(mt, 32));
    const float mnew = fmaxf(m_i, mt);
    const float scl = __expf(m_i - mnew);
    m_i = mnew;
    float ls = 0.f;
#pragma unroll
    for (int r = 0; r < 16; ++r) { p[r] = __expf(p[r] - mnew); ls += p[r]; }
    ls += __shfl_xor(ls, 32);
    l_i = l_i * scl + ls;
    oacc[0] *= scl;
    oacc[1] *= scl;
    // ---- P^T -> B-frags in-register (cvt_pk + permlane32_swap, T12) ----
    // B-frag k=kv: kk*16 + hi*8 + t; lane holds kv=(r&3)+8*(r>>2)+4*hi.
    uint32_t x0, y0, z0, w0, x1, y1, z1, w1;
    asm("v_cvt_pk_bf16_f32 %0, %1, %2" : "=v"(x0) : "v"(p[0]),  "v"(p[1]));
    asm("v_cvt_pk_bf16_f32 %0, %1, %2" : "=v"(y0) : "v"(p[4]),  "v"(p[5]));
    asm("v_cvt_pk_bf16_f32 %0, %1, %2" : "=v"(z0) : "v"(p[2]),  "v"(p[3]));
    asm("v_cvt_pk_bf16_f32 %0, %1, %2" : "=v"(w0) : "v"(p[6]),  "v"(p[7]));
    asm("v_cvt_pk_bf16_f32 %0, %1, %2" : "=v"(x1) : "v"(p[8]),  "v"(p[9]));
    asm("v_cvt_pk_bf16_f32 %0, %1, %2" : "=v"(y1) : "v"(p[12]), "v"(p[13]));
    asm("v_cvt_pk_bf16_f32 %0, %1, %2" : "=v"(z1) : "v"(p[10]), "v"(p[11]));
    asm("v_cvt_pk_bf16_f32 %0, %1, %2" : "=v"(w1) : "v"(p[14]), "v"(p[15]));
    asm("v_permlane32_swap_b32 %0, %1" : "+v"(x0), "+v"(y0));
    asm("v_permlane32_swap_b32 %0, %1" : "+v"(z0), "+v"(w0));
    asm("v_permlane32_swap_b32 %0, %1" : "+v"(x1), "+v"(y1));
    asm("v_permlane32_swap_b32 %0, %1" : "+v"(z1), "+v"(w1));
    u32x4 pb0 = { x0, z0, y0, w0 };   // t=(0,1),(2,3),(4,5),(6,7) for kv kk=0
    u32x4 pb1 = { x1, z1, y1, w1 };   // same for kv kk=1
    const bf16x8 pf0 = *reinterpret_cast<const bf16x8*>(&pb0);
    const bf16x8 pf1 = *reinterpret_cast<const bf16x8*>(&pb1);
    // ---- PV: O^T[dt] += V^T-frag x P^T-frag ----
#pragma unroll
    for (int dt = 0; dt < 2; ++dt) {
      bf16x8 vf0 = *(const bf16x8*)(Vp + (size_t)(dt * 32 + lq) * 1024 + kv0 + hi * 8);
      oacc[dt] = __builtin_amdgcn_mfma_f32_32x32x16_bf16(vf0, pf0, oacc[dt], 0, 0, 0);
      bf16x8 vf1 = *(const bf16x8*)(Vp + (size_t)(dt * 32 + lq) * 1024 + kv0 + 16 + hi * 8);
      oacc[dt] = __builtin_amdgcn_mfma_f32_32x32x16_bf16(vf1, pf1, oacc[dt], 0, 0, 0);
    }
  }
  // ---- write ctx: lane owns q=q0+lq, 32 d values at rows dt*32+crow(r,hi) ----
  const int b = bh >> 4, h = bh & 15;
  const float inv_l = 1.f / l_i;
  bf16_t* crow_p = ctx + ((size_t)(b * 1024 + q0 + lq)) * 1024 + h * 64;
#pragma unroll
  for (int dt = 0; dt < 2; ++dt)
#pragma unroll
    for (int r = 0; r < 16; ++r) {
      const int d = dt * 32 + (r & 3) + 8 * (r >> 2) + 4 * hi;
      crow_p[d] = (bf16_t)(oacc[dt][r] * inv_l);
    }
}

// ---------------- row LayerNorm (D=1024), fp32 in, fp32 + optional bf16 out ----------------
__global__ __launch_bounds__(256) void ln_fwd(const float* __restrict__ in,
                                              const float* __restrict__ gw,
                                              const float* __restrict__ bw,
                                              float* __restrict__ outf,
                                              bf16_t* __restrict__ outb)
{
  const int row = blockIdx.x;
  const float4 v = ((const float4*)(in + (size_t)row * 1024))[threadIdx.x];
  float s  = v.x + v.y + v.z + v.w;
  float ss = v.x * v.x + v.y * v.y + v.z * v.z + v.w * v.w;
#pragma unroll
  for (int o = 32; o > 0; o >>= 1) {
    s  += __shfl_down(s, o);
    ss += __shfl_down(ss, o);
  }
  __shared__ float rs[4], rss[4];
  const int wid = threadIdx.x >> 6, lane = threadIdx.x & 63;
  if (lane == 0) { rs[wid] = s; rss[wid] = ss; }
  __syncthreads();
  const float S  = rs[0] + rs[1] + rs[2] + rs[3];
  const float SS = rss[0] + rss[1] + rss[2] + rss[3];
  const float mu = S * (1.f / 1024.f);
  const float var = SS * (1.f / 1024.f) - mu * mu;
  const float rstd = rsqrtf(var + 1e-7f);
  const float4 g4 = ((const float4*)gw)[threadIdx.x];
  const float4 b4 = ((const float4*)bw)[threadIdx.x];
  float4 o;
  o.x = (v.x - mu) * rstd * g4.x + b4.x;
  o.y = (v.y - mu) * rstd * g4.y + b4.y;
  o.z = (v.z - mu) * rstd * g4.z + b4.z;
  o.w = (v.w - mu) * rstd * g4.w + b4.w;
  if (outf) ((float4*)(outf + (size_t)row * 1024))[threadIdx.x] = o;
  if (outb) {
    bf16x4 ob = { (bf16_t)o.x, (bf16_t)o.y, (bf16_t)o.z, (bf16_t)o.w };
    *(bf16x4*)(outb + (size_t)row * 1024 + threadIdx.x * 4) = ob;
  }
}

// ---------------- launch ----------------
extern "C" void kernel_launch(void* const* d_in, const int* in_sizes, int n_in,
                              void* d_out, int out_size, void* d_ws, size_t ws_size,
                              hipStream_t stream) {
  (void)in_sizes; (void)n_in; (void)out_size; (void)ws_size;
  const float* X   = (const float*)d_in[0];
  const float* Wq  = (const float*)d_in[1];
  const float* bq  = (const float*)d_in[2];
  const float* Wk  = (const float*)d_in[3];
  const float* bk  = (const float*)d_in[4];
  const float* Wv  = (const float*)d_in[5];
  const float* bv  = (const float*)d_in[6];
  const float* Wo  = (const float*)d_in[7];
  const float* bo  = (const float*)d_in[8];
  const float* g1  = (const float*)d_in[9];
  const float* b1  = (const float*)d_in[10];
  const float* Wup = (const float*)d_in[11];
  const float* bup = (const float*)d_in[12];
  const float* Wdn = (const float*)d_in[13];
  const float* bdn = (const float*)d_in[14];
  const float* g2  = (const float*)d_in[15];
  const float* b2  = (const float*)d_in[16];
  float* out = (float*)d_out;

  char* w = (char*)d_ws;
  auto carve = [&](size_t bytes) { char* p = w; w += (bytes + 255) & ~255ull; return p; };
  bf16_t* Xb    = (bf16_t*)carve(4096ull * 1024 * 2);
  bf16_t* Wqkvb = (bf16_t*)carve(3072ull * 1024 * 2);
  bf16_t* Wob   = (bf16_t*)carve(1024ull * 1024 * 2);
  bf16_t* Wupb  = (bf16_t*)carve(4096ull * 1024 * 2);
  bf16_t* Wdnb  = (bf16_t*)carve(1024ull * 4096 * 2);
  bf16_t* Qb    = (bf16_t*)carve(64ull * 1024 * 64 * 2);
  bf16_t* Kb    = (bf16_t*)carve(64ull * 1024 * 64 * 2);
  bf16_t* VTb   = (bf16_t*)carve(64ull * 64 * 1024 * 2);
  bf16_t* CTXb  = (bf16_t*)carve(4096ull * 1024 * 2);
  bf16_t* X1b   = (bf16_t*)carve(4096ull * 1024 * 2);
  bf16_t* UPb   = (bf16_t*)carve(4096ull * 4096 * 2);
  float*  bias3 = (float*) carve(3072ull * 4);
  float*  res1  = (float*) carve(4096ull * 1024 * 4);   // reused for res2
  float*  X1f   = (float*) carve(4096ull * 1024 * 4);

  cvt_f32_bf16<<<4096, 256, 0, stream>>>(X,   Xb, 4096 * 1024);
  cvt_f32_bf16<<<1024, 256, 0, stream>>>(Wq,  Wqkvb,               1024 * 1024);
  cvt_f32_bf16<<<1024, 256, 0, stream>>>(Wk,  Wqkvb + 1024 * 1024, 1024 * 1024);
  cvt_f32_bf16<<<1024, 256, 0, stream>>>(Wv,  Wqkvb + 2048 * 1024, 1024 * 1024);
  cvt_f32_bf16<<<1024, 256, 0, stream>>>(Wo,  Wob,  1024 * 1024);
  cvt_f32_bf16<<<4096, 256, 0, stream>>>(Wup, Wupb, 4096 * 1024);
  cvt_f32_bf16<<<4096, 256, 0, stream>>>(Wdn, Wdnb, 1024 * 4096);
  pack_bias3<<<12, 256, 0, stream>>>(bq, bk, bv, bias3);

  // QKV projection + scatter (V transposed per head)
  gemm_bt<0><<<32 * 24, 256, 0, stream>>>(Xb, Wqkvb, bias3, nullptr,
                                          nullptr, Qb, Kb, VTb, 4096, 3072, 1024);
  // causal flash attention (swapped-operand 32x32, balanced blocks)
  attn_fwd2<<<dim3(8, 64), 256, 0, stream>>>(Qb, Kb, VTb, CTXb);
  // O projection + residual (X) -> res1 (fp32)
  gemm_bt<1><<<32 * 8, 256, 0, stream>>>(CTXb, Wob, bo, X,
                                         res1, nullptr, nullptr, nullptr, 4096, 1024, 1024);
  // LN1 -> X1 fp32 + bf16
  ln_fwd<<<4096, 256, 0, stream>>>(res1, g1, b1, X1f, X1b);
  // FFN up + exact GELU -> bf16
  gemm_bt<2><<<32 * 32, 256, 0, stream>>>(X1b, Wupb, bup, nullptr,
                                          nullptr, UPb, nullptr, nullptr, 4096, 4096, 1024);
  // FFN down + residual (X1) -> res1 (fp32, reuse)
  gemm_bt<3><<<32 * 8, 256, 0, stream>>>(UPb, Wdnb, bdn, X1f,
                                         res1, nullptr, nullptr, nullptr, 4096, 1024, 4096);
  // LN2 -> output fp32
  ln_fwd<<<4096, 256, 0, stream>>>(res1, g2, b2, out, nullptr);
}

// Round 8
// 410.868 us; speedup vs baseline: 1.2216x; 1.0599x over previous
//
#include <hip/hip_runtime.h>
#include <cstdint>

// Fused decoder layer, bf16 MFMA pipeline.
// B=4 S=1024 D=1024 H=16 HD=64, rows R=4096.

typedef __bf16 bf16_t;
typedef __bf16 bf16x8 __attribute__((ext_vector_type(8)));
typedef __bf16 bf16x4 __attribute__((ext_vector_type(4)));
typedef float  f32x4  __attribute__((ext_vector_type(4)));
typedef float  f32x16 __attribute__((ext_vector_type(16)));
typedef uint32_t u32x4 __attribute__((ext_vector_type(4)));

static __device__ __forceinline__ void g2l16(const void* g, void* l) {
  // global -> LDS direct copy, 16B per lane; dst is wave-uniform base, HW adds lane*16.
  __builtin_amdgcn_global_load_lds(
      (__attribute__((address_space(1))) void*)(uintptr_t)g,
      (__attribute__((address_space(3))) void*)l, 16, 0, 0);
}

// ---------------- conversion & packing ----------------
__global__ __launch_bounds__(256) void cvt_f32_bf16(const float* __restrict__ in,
                                                    bf16_t* __restrict__ out, int n) {
  int i = (blockIdx.x * 256 + threadIdx.x) * 4;
  if (i >= n) return;
  float4 v = *(const float4*)(in + i);
  bf16x4 o = { (bf16_t)v.x, (bf16_t)v.y, (bf16_t)v.z, (bf16_t)v.w };
  *(bf16x4*)(out + i) = o;
}

__global__ __launch_bounds__(256) void pack_bias3(const float* __restrict__ a,
                                                  const float* __restrict__ b,
                                                  const float* __restrict__ c,
                                                  float* __restrict__ o) {
  int i = blockIdx.x * 256 + threadIdx.x;  // 0..3071
  o[i] = (i < 1024) ? a[i] : (i < 2048 ? b[i - 1024] : c[i - 2048]);
}

// ---------------- GEMM: C[M,N] = A[M,K] @ Bt[N,K]^T (+epilogue) ----------------
// 128x128 tile, BK=32, 4 waves (2x2), each wave 64x64 = 4x4 MFMA 16x16x32 frags.
// DOUBLE-BUFFERED staging (T3-minimum): stage tile k+1 BEFORE computing tile k,
// one __syncthreads per K-iter (its implicit vmcnt(0) drains the in-flight stage
// which had the whole ds_read+MFMA phase to fly).
// EPI: 0=QKV scatter (bf16, V transposed per head), 1=Wo(+resid fp32 out),
//      2=up(GELU, bf16 out), 3=down(+resid fp32 out)
template<int EPI>
__global__ __launch_bounds__(256) void gemm_bt(
    const bf16_t* __restrict__ A, const bf16_t* __restrict__ Bt,
    const float* __restrict__ bias, const float* __restrict__ resid,
    float* __restrict__ outf, bf16_t* __restrict__ outb,
    bf16_t* __restrict__ outb2, bf16_t* __restrict__ outb3,
    int M, int N, int K)
{
  __shared__ __align__(16) bf16_t As[2][128 * 32];
  __shared__ __align__(16) bf16_t Bs[2][128 * 32];
  const int nbm = M >> 7;
  const int bm = blockIdx.x % nbm;       // consecutive blocks share the B (weight) panel
  const int bn = blockIdx.x / nbm;
  const int lane = threadIdx.x & 63, wid = threadIdx.x >> 6;
  const int wm = wid >> 1, wn = wid & 1;
  const int lr = lane & 15, lk = lane >> 4;   // frag row / k-group
  const int rowA0 = bm * 128, rowB0 = bn * 128;

  f32x4 acc[4][4] = {};

  // staging geometry: tile = 128 rows x 64B; wave stages 2x1024B segments of each tile
  const int seg0 = (wid * 2) * 1024;
  const int boff0 = seg0 + lane * 16;          // byte offset in tile, lane's first 16B
  const int r0 = boff0 >> 6, cb0 = (boff0 & 63) >> 1;   // row, col(elem) in tile
  const int boff1 = boff0 + 1024;
  const int r1 = boff1 >> 6, cb1 = (boff1 & 63) >> 1;

  const bf16_t* Ap0 = A  + (size_t)(rowA0 + r0) * K + cb0;
  const bf16_t* Ap1 = A  + (size_t)(rowA0 + r1) * K + cb1;
  const bf16_t* Bp0 = Bt + (size_t)(rowB0 + r0) * K + cb0;
  const bf16_t* Bp1 = Bt + (size_t)(rowB0 + r1) * K + cb1;

  auto stage = [&](int buf, int k0) {
    g2l16(Ap0 + k0, (char*)As[buf] + seg0);
    g2l16(Ap1 + k0, (char*)As[buf] + seg0 + 1024);
    g2l16(Bp0 + k0, (char*)Bs[buf] + seg0);
    g2l16(Bp1 + k0, (char*)Bs[buf] + seg0 + 1024);
  };

  const int nk = K >> 5;
  stage(0, 0);
  __syncthreads();

  for (int kt = 0; kt < nk; ++kt) {
    const int cur = kt & 1;
    if (kt + 1 < nk) stage(cur ^ 1, (kt + 1) << 5);   // prefetch next tile (async, vmcnt)
    bf16x8 af[4], bb[4];
#pragma unroll
    for (int i = 0; i < 4; ++i)
      af[i] = *(const bf16x8*)(As[cur] + (wm * 64 + i * 16 + lr) * 32 + lk * 8);
#pragma unroll
    for (int j = 0; j < 4; ++j)
      bb[j] = *(const bf16x8*)(Bs[cur] + (wn * 64 + j * 16 + lr) * 32 + lk * 8);
#pragma unroll
    for (int i = 0; i < 4; ++i)
#pragma unroll
      for (int j = 0; j < 4; ++j)
        acc[i][j] = __builtin_amdgcn_mfma_f32_16x16x32_bf16(af[i], bb[j], acc[i][j], 0, 0, 0);
    __syncthreads();   // drains prefetch (vmcnt 0) + guards buf reuse
  }

  // epilogue: C frag mapping col=lane&15, row=(lane>>4)*4+t  [m89-verified]
#pragma unroll
  for (int i = 0; i < 4; ++i) {
    const int grb = bm * 128 + wm * 64 + i * 16 + lk * 4;
#pragma unroll
    for (int j = 0; j < 4; ++j) {
      const int gc = bn * 128 + wn * 64 + j * 16 + lr;
#pragma unroll
      for (int t = 0; t < 4; ++t) {
        const int gr = grb + t;
        float v = acc[i][j][t];
        if (EPI == 0) {
          v += bias[gc];
          const int which = gc >> 10, w2 = gc & 1023, h = w2 >> 6, hd = w2 & 63;
          const int b = gr >> 10, s = gr & 1023;
          const bf16_t bv = (bf16_t)v;
          if (which == 0)      outb [(((size_t)b * 16 + h) * 1024 + s) * 64 + hd] = bv;
          else if (which == 1) outb2[(((size_t)b * 16 + h) * 1024 + s) * 64 + hd] = bv;
          else                 outb3[(((size_t)b * 16 + h) * 64 + hd) * 1024 + s] = bv; // V^T
        } else if (EPI == 1 || EPI == 3) {
          v += bias[gc] + resid[(size_t)gr * N + gc];
          outf[(size_t)gr * N + gc] = v;
        } else {  // EPI == 2: exact GELU
          v += bias[gc];
          const float gelu = 0.5f * v * (1.0f + erff(v * 0.70710678118654752440f));
          outb[(size_t)gr * N + gc] = (bf16_t)gelu;
        }
      }
    }
  }
}

// ---------------- flash attention (causal), swapped-operand 32x32 ----------------
// grid (8, B*H), 256 thr = 4 independent waves; wave owns one 32-row q-tile.
// Block bx owns q-tiles {2bx, 2bx+1, 30-2bx, 31-2bx} -> exactly 66 tile-iters/block.
// Q,K: [bh][s][64] bf16; V: [bh][64][s] bf16 (d-major); ctx out: [b*s][h*64+hd] bf16.
// S^T = mfma(A=K, B=Q): lane q=lane&31, kv=(r&3)+8*(r>>2)+4*hi (m74/m101 layout).
// O^T = mfma(A=V^T, B=P^T): lane q=lane&31 again -> softmax state stays lane-local.
__global__ __launch_bounds__(256) void attn_fwd2(
    const bf16_t* __restrict__ Q, const bf16_t* __restrict__ Kv,
    const bf16_t* __restrict__ VT, bf16_t* __restrict__ ctx)
{
  const int bx = blockIdx.x, bh = blockIdx.y;
  const int lane = threadIdx.x & 63, wid = threadIdx.x >> 6;
  const int lq = lane & 31, hi = lane >> 5;
  const int qt = (wid < 2) ? (2 * bx + wid) : (28 - 2 * bx + wid); // wid2->30-2bx, wid3->31-2bx
  const int q0 = qt * 32;
  const bf16_t* Qp = Q  + (size_t)bh * 1024 * 64;
  const bf16_t* Kp = Kv + (size_t)bh * 1024 * 64;
  const bf16_t* Vp = VT + (size_t)bh * 64 * 1024;

  // Q B-frags (col=q=lane&31, k=d=(db*16 + hi*8 + t)), resident all kernel
  bf16x8 qf[4];
#pragma unroll
  for (int db = 0; db < 4; ++db)
    qf[db] = *(const bf16x8*)(Qp + (size_t)(q0 + lq) * 64 + db * 16 + hi * 8);

  f32x16 oacc[2] = {};          // O^T tiles dt=0,1: row d=dt*32+crow(r,hi), col q=lq
  float m_i = -1e30f, l_i = 0.f;

  const int ntiles = qt + 1;
  for (int kt = 0; kt < ntiles; ++kt) {
    const int kv0 = kt << 5;
    // ---- QK^T (S^T[kv][q]) ----
    f32x16 s = {};
#pragma unroll
    for (int db = 0; db < 4; ++db) {
      bf16x8 kf = *(const bf16x8*)(Kp + (size_t)(kv0 + lq) * 64 + db * 16 + hi * 8);
      s = __builtin_amdgcn_mfma_f32_32x32x16_bf16(kf, qf[db], s, 0, 0, 0);
    }
    // ---- scale + causal mask (only diagonal tile needs masking) ----
    float p[16];
    const bool diag = (kv0 == q0);
#pragma unroll
    for (int r = 0; r < 16; ++r) {
      float v = s[r] * 0.125f;                       // 1/sqrt(64)
      if (diag) {
        const int kvr = (r & 3) + 8 * (r >> 2) + 4 * hi;
        if (kvr > lq) v = -1e30f;
      }
      p[r] = v;
    }
    // ---- online softmax, q = lane&31 (one shfl to merge hi-halves) ----
    float mt = p[0];
#pragma unroll
    for (int r = 1; r < 16; ++r) mt = fmaxf(mt, p[r]);
    mt = fmaxf(mt, __shfl_xor(mt, 32));
    const float mnew = fmaxf(m_i, mt);
    const float scl = __expf(m_i - mnew);
    m_i = mnew;
    float ls = 0.f;
#pragma unroll
    for (int r = 0; r < 16; ++r) { p[r] = __expf(p[r] - mnew); ls += p[r]; }
    ls += __shfl_xor(ls, 32);
    l_i = l_i * scl + ls;
    oacc[0] *= scl;
    oacc[1] *= scl;
    // ---- P^T -> B-frags in-register (cvt_pk + permlane32_swap, T12) ----
    // B-frag k=kv: kk*16 + hi*8 + t; lane holds kv=(r&3)+8*(r>>2)+4*hi.
    uint32_t x0, y0, z0, w0, x1, y1, z1, w1;
    asm("v_cvt_pk_bf16_f32 %0, %1, %2" : "=v"(x0) : "v"(p[0]),  "v"(p[1]));
    asm("v_cvt_pk_bf16_f32 %0, %1, %2" : "=v"(y0) : "v"(p[4]),  "v"(p[5]));
    asm("v_cvt_pk_bf16_f32 %0, %1, %2" : "=v"(z0) : "v"(p[2]),  "v"(p[3]));
    asm("v_cvt_pk_bf16_f32 %0, %1, %2" : "=v"(w0) : "v"(p[6]),  "v"(p[7]));
    asm("v_cvt_pk_bf16_f32 %0, %1, %2" : "=v"(x1) : "v"(p[8]),  "v"(p[9]));
    asm("v_cvt_pk_bf16_f32 %0, %1, %2" : "=v"(y1) : "v"(p[12]), "v"(p[13]));
    asm("v_cvt_pk_bf16_f32 %0, %1, %2" : "=v"(z1) : "v"(p[10]), "v"(p[11]));
    asm("v_cvt_pk_bf16_f32 %0, %1, %2" : "=v"(w1) : "v"(p[14]), "v"(p[15]));
    asm("v_permlane32_swap_b32 %0, %1" : "+v"(x0), "+v"(y0));
    asm("v_permlane32_swap_b32 %0, %1" : "+v"(z0), "+v"(w0));
    asm("v_permlane32_swap_b32 %0, %1" : "+v"(x1), "+v"(y1));
    asm("v_permlane32_swap_b32 %0, %1" : "+v"(z1), "+v"(w1));
    u32x4 pb0 = { x0, z0, y0, w0 };   // t=(0,1),(2,3),(4,5),(6,7) for kv kk=0
    u32x4 pb1 = { x1, z1, y1, w1 };   // same for kv kk=1
    const bf16x8 pf0 = *reinterpret_cast<const bf16x8*>(&pb0);
    const bf16x8 pf1 = *reinterpret_cast<const bf16x8*>(&pb1);
    // ---- PV: O^T[dt] += V^T-frag x P^T-frag ----
#pragma unroll
    for (int dt = 0; dt < 2; ++dt) {
      bf16x8 vf0 = *(const bf16x8*)(Vp + (size_t)(dt * 32 + lq) * 1024 + kv0 + hi * 8);
      oacc[dt] = __builtin_amdgcn_mfma_f32_32x32x16_bf16(vf0, pf0, oacc[dt], 0, 0, 0);
      bf16x8 vf1 = *(const bf16x8*)(Vp + (size_t)(dt * 32 + lq) * 1024 + kv0 + 16 + hi * 8);
      oacc[dt] = __builtin_amdgcn_mfma_f32_32x32x16_bf16(vf1, pf1, oacc[dt], 0, 0, 0);
    }
  }
  // ---- write ctx: lane owns q=q0+lq, 32 d values at rows dt*32+crow(r,hi) ----
  const int b = bh >> 4, h = bh & 15;
  const float inv_l = 1.f / l_i;
  bf16_t* crow_p = ctx + ((size_t)(b * 1024 + q0 + lq)) * 1024 + h * 64;
#pragma unroll
  for (int dt = 0; dt < 2; ++dt)
#pragma unroll
    for (int r = 0; r < 16; ++r) {
      const int d = dt * 32 + (r & 3) + 8 * (r >> 2) + 4 * hi;
      crow_p[d] = (bf16_t)(oacc[dt][r] * inv_l);
    }
}

// ---------------- row LayerNorm (D=1024), fp32 in, fp32 + optional bf16 out ----------------
__global__ __launch_bounds__(256) void ln_fwd(const float* __restrict__ in,
                                              const float* __restrict__ gw,
                                              const float* __restrict__ bw,
                                              float* __restrict__ outf,
                                              bf16_t* __restrict__ outb)
{
  const int row = blockIdx.x;
  const float4 v = ((const float4*)(in + (size_t)row * 1024))[threadIdx.x];
  float s  = v.x + v.y + v.z + v.w;
  float ss = v.x * v.x + v.y * v.y + v.z * v.z + v.w * v.w;
#pragma unroll
  for (int o = 32; o > 0; o >>= 1) {
    s  += __shfl_down(s, o);
    ss += __shfl_down(ss, o);
  }
  __shared__ float rs[4], rss[4];
  const int wid = threadIdx.x >> 6, lane = threadIdx.x & 63;
  if (lane == 0) { rs[wid] = s; rss[wid] = ss; }
  __syncthreads();
  const float S  = rs[0] + rs[1] + rs[2] + rs[3];
  const float SS = rss[0] + rss[1] + rss[2] + rss[3];
  const float mu = S * (1.f / 1024.f);
  const float var = SS * (1.f / 1024.f) - mu * mu;
  const float rstd = rsqrtf(var + 1e-7f);
  const float4 g4 = ((const float4*)gw)[threadIdx.x];
  const float4 b4 = ((const float4*)bw)[threadIdx.x];
  float4 o;
  o.x = (v.x - mu) * rstd * g4.x + b4.x;
  o.y = (v.y - mu) * rstd * g4.y + b4.y;
  o.z = (v.z - mu) * rstd * g4.z + b4.z;
  o.w = (v.w - mu) * rstd * g4.w + b4.w;
  if (outf) ((float4*)(outf + (size_t)row * 1024))[threadIdx.x] = o;
  if (outb) {
    bf16x4 ob = { (bf16_t)o.x, (bf16_t)o.y, (bf16_t)o.z, (bf16_t)o.w };
    *(bf16x4*)(outb + (size_t)row * 1024 + threadIdx.x * 4) = ob;
  }
}

// ---------------- launch ----------------
extern "C" void kernel_launch(void* const* d_in, const int* in_sizes, int n_in,
                              void* d_out, int out_size, void* d_ws, size_t ws_size,
                              hipStream_t stream) {
  (void)in_sizes; (void)n_in; (void)out_size; (void)ws_size;
  const float* X   = (const float*)d_in[0];
  const float* Wq  = (const float*)d_in[1];
  const float* bq  = (const float*)d_in[2];
  const float* Wk  = (const float*)d_in[3];
  const float* bk  = (const float*)d_in[4];
  const float* Wv  = (const float*)d_in[5];
  const float* bv  = (const float*)d_in[6];
  const float* Wo  = (const float*)d_in[7];
  const float* bo  = (const float*)d_in[8];
  const float* g1  = (const float*)d_in[9];
  const float* b1  = (const float*)d_in[10];
  const float* Wup = (const float*)d_in[11];
  const float* bup = (const float*)d_in[12];
  const float* Wdn = (const float*)d_in[13];
  const float* bdn = (const float*)d_in[14];
  const float* g2  = (const float*)d_in[15];
  const float* b2  = (const float*)d_in[16];
  float* out = (float*)d_out;

  char* w = (char*)d_ws;
  auto carve = [&](size_t bytes) { char* p = w; w += (bytes + 255) & ~255ull; return p; };
  bf16_t* Xb    = (bf16_t*)carve(4096ull * 1024 * 2);
  bf16_t* Wqkvb = (bf16_t*)carve(3072ull * 1024 * 2);
  bf16_t* Wob   = (bf16_t*)carve(1024ull * 1024 * 2);
  bf16_t* Wupb  = (bf16_t*)carve(4096ull * 1024 * 2);
  bf16_t* Wdnb  = (bf16_t*)carve(1024ull * 4096 * 2);
  bf16_t* Qb    = (bf16_t*)carve(64ull * 1024 * 64 * 2);
  bf16_t* Kb    = (bf16_t*)carve(64ull * 1024 * 64 * 2);
  bf16_t* VTb   = (bf16_t*)carve(64ull * 64 * 1024 * 2);
  bf16_t* CTXb  = (bf16_t*)carve(4096ull * 1024 * 2);
  bf16_t* X1b   = (bf16_t*)carve(4096ull * 1024 * 2);
  bf16_t* UPb   = (bf16_t*)carve(4096ull * 4096 * 2);
  float*  bias3 = (float*) carve(3072ull * 4);
  float*  res1  = (float*) carve(4096ull * 1024 * 4);   // reused for res2
  float*  X1f   = (float*) carve(4096ull * 1024 * 4);

  cvt_f32_bf16<<<4096, 256, 0, stream>>>(X,   Xb, 4096 * 1024);
  cvt_f32_bf16<<<1024, 256, 0, stream>>>(Wq,  Wqkvb,               1024 * 1024);
  cvt_f32_bf16<<<1024, 256, 0, stream>>>(Wk,  Wqkvb + 1024 * 1024, 1024 * 1024);
  cvt_f32_bf16<<<1024, 256, 0, stream>>>(Wv,  Wqkvb + 2048 * 1024, 1024 * 1024);
  cvt_f32_bf16<<<1024, 256, 0, stream>>>(Wo,  Wob,  1024 * 1024);
  cvt_f32_bf16<<<4096, 256, 0, stream>>>(Wup, Wupb, 4096 * 1024);
  cvt_f32_bf16<<<4096, 256, 0, stream>>>(Wdn, Wdnb, 1024 * 4096);
  pack_bias3<<<12, 256, 0, stream>>>(bq, bk, bv, bias3);

  // QKV projection + scatter (V transposed per head)
  gemm_bt<0><<<32 * 24, 256, 0, stream>>>(Xb, Wqkvb, bias3, nullptr,
                                          nullptr, Qb, Kb, VTb, 4096, 3072, 1024);
  // causal flash attention (swapped-operand 32x32, balanced blocks)
  attn_fwd2<<<dim3(8, 64), 256, 0, stream>>>(Qb, Kb, VTb, CTXb);
  // O projection + residual (X) -> res1 (fp32)
  gemm_bt<1><<<32 * 8, 256, 0, stream>>>(CTXb, Wob, bo, X,
                                         res1, nullptr, nullptr, nullptr, 4096, 1024, 1024);
  // LN1 -> X1 fp32 + bf16
  ln_fwd<<<4096, 256, 0, stream>>>(res1, g1, b1, X1f, X1b);
  // FFN up + exact GELU -> bf16
  gemm_bt<2><<<32 * 32, 256, 0, stream>>>(X1b, Wupb, bup, nullptr,
                                          nullptr, UPb, nullptr, nullptr, 4096, 4096, 1024);
  // FFN down + residual (X1) -> res1 (fp32, reuse)
  gemm_bt<3><<<32 * 8, 256, 0, stream>>>(UPb, Wdnb, bdn, X1f,
                                         res1, nullptr, nullptr, nullptr, 4096, 1024, 4096);
  // LN2 -> output fp32
  ln_fwd<<<4096, 256, 0, stream>>>(res1, g2, b2, out, nullptr);
}

// Round 10
// 395.204 us; speedup vs baseline: 1.2701x; 1.0396x over previous
//
#include <hip/hip_runtime.h>
#include <cstdint>

// Fused decoder layer, bf16 MFMA pipeline.
// B=4 S=1024 D=1024 H=16 HD=64, rows R=4096.

typedef __bf16 bf16_t;
typedef __bf16 bf16x8 __attribute__((ext_vector_type(8)));
typedef __bf16 bf16x4 __attribute__((ext_vector_type(4)));
typedef float  f32x4  __attribute__((ext_vector_type(4)));
typedef float  f32x16 __attribute__((ext_vector_type(16)));
typedef uint32_t u32x4 __attribute__((ext_vector_type(4)));

static __device__ __forceinline__ void g2l16(const void* g, void* l) {
  // global -> LDS direct copy, 16B per lane; dst is wave-uniform base, HW adds lane*16.
  __builtin_amdgcn_global_load_lds(
      (__attribute__((address_space(1))) void*)(uintptr_t)g,
      (__attribute__((address_space(3))) void*)l, 16, 0, 0);
}

// ---------------- conversion & packing ----------------
__global__ __launch_bounds__(256) void cvt_f32_bf16(const float* __restrict__ in,
                                                    bf16_t* __restrict__ out, int n) {
  int i = (blockIdx.x * 256 + threadIdx.x) * 4;
  if (i >= n) return;
  float4 v = *(const float4*)(in + i);
  bf16x4 o = { (bf16_t)v.x, (bf16_t)v.y, (bf16_t)v.z, (bf16_t)v.w };
  *(bf16x4*)(out + i) = o;
}

__global__ __launch_bounds__(256) void pack_bias3(const float* __restrict__ a,
                                                  const float* __restrict__ b,
                                                  const float* __restrict__ c,
                                                  float* __restrict__ o) {
  int i = blockIdx.x * 256 + threadIdx.x;  // 0..3071
  o[i] = (i < 1024) ? a[i] : (i < 2048 ? b[i - 1024] : c[i - 2048]);
}

// ---------------- GEMM: C[M,N] = A[M,K] @ Bt[N,K]^T (+epilogue) ----------------
// 128xBN tile (BN=128 or 64), BK=32, 4 waves (2x2), wave = 64 x BN/2 output.
// DOUBLE-BUFFERED staging: stage tile k+1 BEFORE computing tile k, one
// __syncthreads per K-iter. BN=64 doubles the grid for N=1024 GEMMs -> 2
// blocks/CU so blocks overlap each other's prefetch stalls.
// EPI: 0=QKV scatter (bf16, V transposed per head), 1=Wo(+resid fp32 out),
//      2=up(GELU, bf16 out), 3=down(+resid fp32 out)
template<int EPI, int BN>
__global__ __launch_bounds__(256) void gemm_bt(
    const bf16_t* __restrict__ A, const bf16_t* __restrict__ Bt,
    const float* __restrict__ bias, const float* __restrict__ resid,
    float* __restrict__ outf, bf16_t* __restrict__ outb,
    bf16_t* __restrict__ outb2, bf16_t* __restrict__ outb3,
    int M, int N, int K)
{
  constexpr int NJ   = BN / 32;   // N-frags per wave
  constexpr int BSEG = BN / 64;   // B staging segments (1024B) per wave
  __shared__ __align__(16) bf16_t As[2][128 * 32];
  __shared__ __align__(16) bf16_t Bs[2][BN * 32];
  const int nbm = M >> 7;
  const int bm = blockIdx.x % nbm;       // consecutive blocks share the B (weight) panel
  const int bn = blockIdx.x / nbm;
  const int lane = threadIdx.x & 63, wid = threadIdx.x >> 6;
  const int wm = wid >> 1, wn = wid & 1;
  const int lr = lane & 15, lk = lane >> 4;   // frag row / k-group
  const int rowA0 = bm * 128, rowB0 = bn * BN;

  f32x4 acc[4][NJ] = {};

  // staging geometry: A tile = 128 rows x 64B (8 segs), B tile = BN rows x 64B.
  const int segA = wid * 2 * 1024;
  const int a0 = segA + lane * 16, a1 = a0 + 1024;
  const bf16_t* Ap0 = A + (size_t)(rowA0 + (a0 >> 6)) * K + ((a0 & 63) >> 1);
  const bf16_t* Ap1 = A + (size_t)(rowA0 + (a1 >> 6)) * K + ((a1 & 63) >> 1);
  const int segB = wid * BSEG * 1024;
  const int b0 = segB + lane * 16, b1 = b0 + 1024;
  const bf16_t* Bp0 = Bt + (size_t)(rowB0 + (b0 >> 6)) * K + ((b0 & 63) >> 1);
  const int b1row = (BSEG == 2) ? (rowB0 + (b1 >> 6)) : rowB0;  // guard OOB when BSEG==1
  const bf16_t* Bp1 = Bt + (size_t)b1row * K + ((b1 & 63) >> 1);

  auto stage = [&](int buf, int k0) {
    g2l16(Ap0 + k0, (char*)As[buf] + segA);
    g2l16(Ap1 + k0, (char*)As[buf] + segA + 1024);
    g2l16(Bp0 + k0, (char*)Bs[buf] + segB);
    if constexpr (BSEG == 2) g2l16(Bp1 + k0, (char*)Bs[buf] + segB + 1024);
  };

  const int nk = K >> 5;
  stage(0, 0);
  __syncthreads();

  for (int kt = 0; kt < nk; ++kt) {
    const int cur = kt & 1;
    if (kt + 1 < nk) stage(cur ^ 1, (kt + 1) << 5);   // prefetch next tile (async, vmcnt)
    bf16x8 af[4], bb[NJ];
#pragma unroll
    for (int i = 0; i < 4; ++i)
      af[i] = *(const bf16x8*)(As[cur] + (wm * 64 + i * 16 + lr) * 32 + lk * 8);
#pragma unroll
    for (int j = 0; j < NJ; ++j)
      bb[j] = *(const bf16x8*)(Bs[cur] + (wn * (BN / 2) + j * 16 + lr) * 32 + lk * 8);
#pragma unroll
    for (int i = 0; i < 4; ++i)
#pragma unroll
      for (int j = 0; j < NJ; ++j)
        acc[i][j] = __builtin_amdgcn_mfma_f32_16x16x32_bf16(af[i], bb[j], acc[i][j], 0, 0, 0);
    __syncthreads();   // drains prefetch (vmcnt 0) + guards buf reuse
  }

  // epilogue: C frag mapping col=lane&15, row=(lane>>4)*4+t  [m89-verified]
#pragma unroll
  for (int i = 0; i < 4; ++i) {
    const int grb = bm * 128 + wm * 64 + i * 16 + lk * 4;
#pragma unroll
    for (int j = 0; j < NJ; ++j) {
      const int gc = bn * BN + wn * (BN / 2) + j * 16 + lr;
#pragma unroll
      for (int t = 0; t < 4; ++t) {
        const int gr = grb + t;
        float v = acc[i][j][t];
        if (EPI == 0) {
          v += bias[gc];
          const int which = gc >> 10, w2 = gc & 1023, h = w2 >> 6, hd = w2 & 63;
          const int b = gr >> 10, s = gr & 1023;
          const bf16_t bv = (bf16_t)v;
          if (which == 0)      outb [(((size_t)b * 16 + h) * 1024 + s) * 64 + hd] = bv;
          else if (which == 1) outb2[(((size_t)b * 16 + h) * 1024 + s) * 64 + hd] = bv;
          else                 outb3[(((size_t)b * 16 + h) * 64 + hd) * 1024 + s] = bv; // V^T
        } else if (EPI == 1 || EPI == 3) {
          v += bias[gc] + resid[(size_t)gr * N + gc];
          outf[(size_t)gr * N + gc] = v;
        } else {  // EPI == 2: exact GELU
          v += bias[gc];
          const float gelu = 0.5f * v * (1.0f + erff(v * 0.70710678118654752440f));
          outb[(size_t)gr * N + gc] = (bf16_t)gelu;
        }
      }
    }
  }
}

// ---------------- flash attention (causal), swapped-operand 32x32 ----------------
// grid (8, B*H), 256 thr = 4 independent waves; wave owns one 32-row q-tile.
// Block bx owns q-tiles {2bx, 2bx+1, 30-2bx, 31-2bx} -> exactly 66 tile-iters/block.
// Q,K: [bh][s][64] bf16; V: [bh][64][s] bf16 (d-major); ctx out: [b*s][h*64+hd] bf16.
// S^T = mfma(A=K, B=Q): lane q=lane&31, kv=(r&3)+8*(r>>2)+4*hi (m74/m101 layout).
// O^T = mfma(A=V^T, B=P^T): lane q=lane&31 again -> softmax state stays lane-local.
__global__ __launch_bounds__(256) void attn_fwd2(
    const bf16_t* __restrict__ Q, const bf16_t* __restrict__ Kv,
    const bf16_t* __restrict__ VT, bf16_t* __restrict__ ctx)
{
  const int bx = blockIdx.x, bh = blockIdx.y;
  const int lane = threadIdx.x & 63, wid = threadIdx.x >> 6;
  const int lq = lane & 31, hi = lane >> 5;
  const int qt = (wid < 2) ? (2 * bx + wid) : (28 - 2 * bx + wid); // wid2->30-2bx, wid3->31-2bx
  const int q0 = qt * 32;
  const bf16_t* Qp = Q  + (size_t)bh * 1024 * 64;
  const bf16_t* Kp = Kv + (size_t)bh * 1024 * 64;
  const bf16_t* Vp = VT + (size_t)bh * 64 * 1024;

  // Q B-frags (col=q=lane&31, k=d=(db*16 + hi*8 + t)), resident all kernel
  bf16x8 qf[4];
#pragma unroll
  for (int db = 0; db < 4; ++db)
    qf[db] = *(const bf16x8*)(Qp + (size_t)(q0 + lq) * 64 + db * 16 + hi * 8);

  f32x16 oacc[2] = {};          // O^T tiles dt=0,1: row d=dt*32+crow(r,hi), col q=lq
  float m_i = -1e30f, l_i = 0.f;

  const int ntiles = qt + 1;
  for (int kt = 0; kt < ntiles; ++kt) {
    const int kv0 = kt << 5;
    // ---- QK^T (S^T[kv][q]) ----
    f32x16 s = {};
#pragma unroll
    for (int db = 0; db < 4; ++db) {
      bf16x8 kf = *(const bf16x8*)(Kp + (size_t)(kv0 + lq) * 64 + db * 16 + hi * 8);
      s = __builtin_amdgcn_mfma_f32_32x32x16_bf16(kf, qf[db], s, 0, 0, 0);
    }
    // ---- scale + causal mask (only diagonal tile needs masking) ----
    float p[16];
    const bool diag = (kv0 == q0);
#pragma unroll
    for (int r = 0; r < 16; ++r) {
      float v = s[r] * 0.125f;                       // 1/sqrt(64)
      if (diag) {
        const int kvr = (r & 3) + 8 * (r >> 2) + 4 * hi;
        if (kvr > lq) v = -1e30f;
      }
      p[r] = v;
    }
    // ---- online softmax, q = lane&31 (one shfl to merge hi-halves) ----
    float mt = p[0];
#pragma unroll
    for (int r = 1; r < 16; ++r) mt = fmaxf(mt, p[r]);
    mt = fmaxf(mt, __shfl_xor(mt, 32));
    const float mnew = fmaxf(m_i, mt);
    const float scl = __expf(m_i - mnew);
    m_i = mnew;
    float ls = 0.f;
#pragma unroll
    for (int r = 0; r < 16; ++r) { p[r] = __expf(p[r] - mnew); ls += p[r]; }
    ls += __shfl_xor(ls, 32);
    l_i = l_i * scl + ls;
    oacc[0] *= scl;
    oacc[1] *= scl;
    // ---- P^T -> B-frags in-register (cvt_pk + permlane32_swap, T12) ----
    // B-frag k=kv: kk*16 + hi*8 + t; lane holds kv=(r&3)+8*(r>>2)+4*hi.
    uint32_t x0, y0, z0, w0, x1, y1, z1, w1;
    asm("v_cvt_pk_bf16_f32 %0, %1, %2" : "=v"(x0) : "v"(p[0]),  "v"(p[1]));
    asm("v_cvt_pk_bf16_f32 %0, %1, %2" : "=v"(y0) : "v"(p[4]),  "v"(p[5]));
    asm("v_cvt_pk_bf16_f32 %0, %1, %2" : "=v"(z0) : "v"(p[2]),  "v"(p[3]));
    asm("v_cvt_pk_bf16_f32 %0, %1, %2" : "=v"(w0) : "v"(p[6]),  "v"(p[7]));
    asm("v_cvt_pk_bf16_f32 %0, %1, %2" : "=v"(x1) : "v"(p[8]),  "v"(p[9]));
    asm("v_cvt_pk_bf16_f32 %0, %1, %2" : "=v"(y1) : "v"(p[12]), "v"(p[13]));
    asm("v_cvt_pk_bf16_f32 %0, %1, %2" : "=v"(z1) : "v"(p[10]), "v"(p[11]));
    asm("v_cvt_pk_bf16_f32 %0, %1, %2" : "=v"(w1) : "v"(p[14]), "v"(p[15]));
    asm("v_permlane32_swap_b32 %0, %1" : "+v"(x0), "+v"(y0));
    asm("v_permlane32_swap_b32 %0, %1" : "+v"(z0), "+v"(w0));
    asm("v_permlane32_swap_b32 %0, %1" : "+v"(x1), "+v"(y1));
    asm("v_permlane32_swap_b32 %0, %1" : "+v"(z1), "+v"(w1));
    u32x4 pb0 = { x0, z0, y0, w0 };   // t=(0,1),(2,3),(4,5),(6,7) for kv kk=0
    u32x4 pb1 = { x1, z1, y1, w1 };   // same for kv kk=1
    const bf16x8 pf0 = *reinterpret_cast<const bf16x8*>(&pb0);
    const bf16x8 pf1 = *reinterpret_cast<const bf16x8*>(&pb1);
    // ---- PV: O^T[dt] += V^T-frag x P^T-frag ----
#pragma unroll
    for (int dt = 0; dt < 2; ++dt) {
      bf16x8 vf0 = *(const bf16x8*)(Vp + (size_t)(dt * 32 + lq) * 1024 + kv0 + hi * 8);
      oacc[dt] = __builtin_amdgcn_mfma_f32_32x32x16_bf16(vf0, pf0, oacc[dt], 0, 0, 0);
      bf16x8 vf1 = *(const bf16x8*)(Vp + (size_t)(dt * 32 + lq) * 1024 + kv0 + 16 + hi * 8);
      oacc[dt] = __builtin_amdgcn_mfma_f32_32x32x16_bf16(vf1, pf1, oacc[dt], 0, 0, 0);
    }
  }
  // ---- write ctx: lane owns q=q0+lq, 32 d values at rows dt*32+crow(r,hi) ----
  const int b = bh >> 4, h = bh & 15;
  const float inv_l = 1.f / l_i;
  bf16_t* crow_p = ctx + ((size_t)(b * 1024 + q0 + lq)) * 1024 + h * 64;
#pragma unroll
  for (int dt = 0; dt < 2; ++dt)
#pragma unroll
    for (int r = 0; r < 16; ++r) {
      const int d = dt * 32 + (r & 3) + 8 * (r >> 2) + 4 * hi;
      crow_p[d] = (bf16_t)(oacc[dt][r] * inv_l);
    }
}

// ---------------- row LayerNorm (D=1024), fp32 in, fp32 + optional bf16 out ----------------
__global__ __launch_bounds__(256) void ln_fwd(const float* __restrict__ in,
                                              const float* __restrict__ gw,
                                              const float* __restrict__ bw,
                                              float* __restrict__ outf,
                                              bf16_t* __restrict__ outb)
{
  const int row = blockIdx.x;
  const float4 v = ((const float4*)(in + (size_t)row * 1024))[threadIdx.x];
  float s  = v.x + v.y + v.z + v.w;
  float ss = v.x * v.x + v.y * v.y + v.z * v.z + v.w * v.w;
#pragma unroll
  for (int o = 32; o > 0; o >>= 1) {
    s  += __shfl_down(s, o);
    ss += __shfl_down(ss, o);
  }
  __shared__ float rs[4], rss[4];
  const int wid = threadIdx.x >> 6, lane = threadIdx.x & 63;
  if (lane == 0) { rs[wid] = s; rss[wid] = ss; }
  __syncthreads();
  const float S  = rs[0] + rs[1] + rs[2] + rs[3];
  const float SS = rss[0] + rss[1] + rss[2] + rss[3];
  const float mu = S * (1.f / 1024.f);
  const float var = SS * (1.f / 1024.f) - mu * mu;
  const float rstd = rsqrtf(var + 1e-7f);
  const float4 g4 = ((const float4*)gw)[threadIdx.x];
  const float4 b4 = ((const float4*)bw)[threadIdx.x];
  float4 o;
  o.x = (v.x - mu) * rstd * g4.x + b4.x;
  o.y = (v.y - mu) * rstd * g4.y + b4.y;
  o.z = (v.z - mu) * rstd * g4.z + b4.z;
  o.w = (v.w - mu) * rstd * g4.w + b4.w;
  if (outf) ((float4*)(outf + (size_t)row * 1024))[threadIdx.x] = o;
  if (outb) {
    bf16x4 ob = { (bf16_t)o.x, (bf16_t)o.y, (bf16_t)o.z, (bf16_t)o.w };
    *(bf16x4*)(outb + (size_t)row * 1024 + threadIdx.x * 4) = ob;
  }
}

// ---------------- launch ----------------
extern "C" void kernel_launch(void* const* d_in, const int* in_sizes, int n_in,
                              void* d_out, int out_size, void* d_ws, size_t ws_size,
                              hipStream_t stream) {
  (void)in_sizes; (void)n_in; (void)out_size; (void)ws_size;
  const float* X   = (const float*)d_in[0];
  const float* Wq  = (const float*)d_in[1];
  const float* bq  = (const float*)d_in[2];
  const float* Wk  = (const float*)d_in[3];
  const float* bk  = (const float*)d_in[4];
  const float* Wv  = (const float*)d_in[5];
  const float* bv  = (const float*)d_in[6];
  const float* Wo  = (const float*)d_in[7];
  const float* bo  = (const float*)d_in[8];
  const float* g1  = (const float*)d_in[9];
  const float* b1  = (const float*)d_in[10];
  const float* Wup = (const float*)d_in[11];
  const float* bup = (const float*)d_in[12];
  const float* Wdn = (const float*)d_in[13];
  const float* bdn = (const float*)d_in[14];
  const float* g2  = (const float*)d_in[15];
  const float* b2  = (const float*)d_in[16];
  float* out = (float*)d_out;

  char* w = (char*)d_ws;
  auto carve = [&](size_t bytes) { char* p = w; w += (bytes + 255) & ~255ull; return p; };
  bf16_t* Xb    = (bf16_t*)carve(4096ull * 1024 * 2);
  bf16_t* Wqkvb = (bf16_t*)carve(3072ull * 1024 * 2);
  bf16_t* Wob   = (bf16_t*)carve(1024ull * 1024 * 2);
  bf16_t* Wupb  = (bf16_t*)carve(4096ull * 1024 * 2);
  bf16_t* Wdnb  = (bf16_t*)carve(1024ull * 4096 * 2);
  bf16_t* Qb    = (bf16_t*)carve(64ull * 1024 * 64 * 2);
  bf16_t* Kb    = (bf16_t*)carve(64ull * 1024 * 64 * 2);
  bf16_t* VTb   = (bf16_t*)carve(64ull * 64 * 1024 * 2);
  bf16_t* CTXb  = (bf16_t*)carve(4096ull * 1024 * 2);
  bf16_t* X1b   = (bf16_t*)carve(4096ull * 1024 * 2);
  bf16_t* UPb   = (bf16_t*)carve(4096ull * 4096 * 2);
  float*  bias3 = (float*) carve(3072ull * 4);
  float*  res1  = (float*) carve(4096ull * 1024 * 4);   // reused for res2
  float*  X1f   = (float*) carve(4096ull * 1024 * 4);

  cvt_f32_bf16<<<4096, 256, 0, stream>>>(X,   Xb, 4096 * 1024);
  cvt_f32_bf16<<<1024, 256, 0, stream>>>(Wq,  Wqkvb,               1024 * 1024);
  cvt_f32_bf16<<<1024, 256, 0, stream>>>(Wk,  Wqkvb + 1024 * 1024, 1024 * 1024);
  cvt_f32_bf16<<<1024, 256, 0, stream>>>(Wv,  Wqkvb + 2048 * 1024, 1024 * 1024);
  cvt_f32_bf16<<<1024, 256, 0, stream>>>(Wo,  Wob,  1024 * 1024);
  cvt_f32_bf16<<<4096, 256, 0, stream>>>(Wup, Wupb, 4096 * 1024);
  cvt_f32_bf16<<<4096, 256, 0, stream>>>(Wdn, Wdnb, 1024 * 4096);
  pack_bias3<<<12, 256, 0, stream>>>(bq, bk, bv, bias3);

  // QKV projection + scatter (V transposed per head)  [grid 768 = 3 blocks/CU]
  gemm_bt<0, 128><<<32 * 24, 256, 0, stream>>>(Xb, Wqkvb, bias3, nullptr,
                                               nullptr, Qb, Kb, VTb, 4096, 3072, 1024);
  // causal flash attention (swapped-operand 32x32, balanced blocks)
  attn_fwd2<<<dim3(8, 64), 256, 0, stream>>>(Qb, Kb, VTb, CTXb);
  // O projection + residual (X) -> res1 (fp32)  [BN=64: grid 512 = 2 blocks/CU]
  gemm_bt<1, 64><<<32 * 16, 256, 0, stream>>>(CTXb, Wob, bo, X,
                                              res1, nullptr, nullptr, nullptr, 4096, 1024, 1024);
  // LN1 -> X1 fp32 + bf16
  ln_fwd<<<4096, 256, 0, stream>>>(res1, g1, b1, X1f, X1b);
  // FFN up + exact GELU -> bf16  [grid 1024 = 4 blocks/CU]
  gemm_bt<2, 128><<<32 * 32, 256, 0, stream>>>(X1b, Wupb, bup, nullptr,
                                               nullptr, UPb, nullptr, nullptr, 4096, 4096, 1024);
  // FFN down + residual (X1) -> res1 (fp32, reuse)  [BN=64: grid 512 = 2 blocks/CU]
  gemm_bt<3, 64><<<32 * 16, 256, 0, stream>>>(UPb, Wdnb, bdn, X1f,
                                              res1, nullptr, nullptr, nullptr, 4096, 1024, 4096);
  // LN2 -> output fp32
  ln_fwd<<<4096, 256, 0, stream>>>(res1, g2, b2, out, nullptr);
}